// Round 1
// baseline (461.877 us; speedup 1.0000x reference)
//
#include <hip/hip_runtime.h>

#define B_N 8192
#define D_K 256
#define MARGIN 0.3f

// Order-preserving map float -> uint so atomicMax/atomicMin work on floats
// (including negatives, which occur on the diagonal from rounding).
__device__ __forceinline__ unsigned fkey(float f) {
    unsigned u = __float_as_uint(f);
    return (u & 0x80000000u) ? ~u : (u | 0x80000000u);
}
__device__ __forceinline__ float kval(unsigned k) {
    return (k & 0x80000000u) ? __uint_as_float(k ^ 0x80000000u)
                             : __uint_as_float(~k);
}

// ---------------- kernel 1: row squared norms + init reduce cells ----------
__global__ __launch_bounds__(256) void prep_kernel(const float* __restrict__ X,
        float* __restrict__ sq, unsigned* __restrict__ apk,
        unsigned* __restrict__ ank) {
    int row  = (blockIdx.x << 2) + (threadIdx.x >> 6);  // 4 waves = 4 rows/block
    int lane = threadIdx.x & 63;
    const float4 v = reinterpret_cast<const float4*>(X + (size_t)row * D_K)[lane];
    float s = v.x * v.x + v.y * v.y + v.z * v.z + v.w * v.w;
    #pragma unroll
    for (int off = 32; off > 0; off >>= 1) s += __shfl_down(s, off, 64);
    if (lane == 0) {
        sq[row]  = s;
        apk[row] = 0u;           // <= fkey(-inf)
        ank[row] = 0xFFFFFFFFu;  // >= fkey(+inf)
    }
}

// ---------------- kernel 2: fused distance GEMM + hard mining --------------
#define BM 128
#define BN 128
#define BK 32
#define PAD 4   // multiple of 4 floats: keeps ds_read_b128 alignment

__global__ __launch_bounds__(256) void dist_kernel(const float* __restrict__ X,
        const int* __restrict__ tgt, const float* __restrict__ sq,
        unsigned* __restrict__ apk, unsigned* __restrict__ ank) {
    __shared__ float As[BK][BM + PAD];  // transposed: As[k][m]
    __shared__ float Bs[BK][BN + PAD];  // transposed: Bs[k][n]

    const int bm  = blockIdx.y * BM;
    const int bn  = blockIdx.x * BN;
    const int tid = threadIdx.x;
    const int tx  = tid & 15;   // 16 thread-cols
    const int ty  = tid >> 4;   // 16 thread-rows

    float acc[8][8];
    #pragma unroll
    for (int i = 0; i < 8; ++i)
        #pragma unroll
        for (int j = 0; j < 8; ++j) acc[i][j] = 0.f;

    const int lr = tid >> 3;         // 0..31 : row within tile (per it-step)
    const int lk = (tid & 7) << 2;   // 0,4,...,28 : k offset

    #pragma unroll 1
    for (int k0 = 0; k0 < D_K; k0 += BK) {
        #pragma unroll
        for (int it = 0; it < 4; ++it) {
            int r = lr + (it << 5);  // 0..127
            float4 va = *reinterpret_cast<const float4*>(
                X + (size_t)(bm + r) * D_K + k0 + lk);
            As[lk + 0][r] = va.x; As[lk + 1][r] = va.y;
            As[lk + 2][r] = va.z; As[lk + 3][r] = va.w;
            float4 vb = *reinterpret_cast<const float4*>(
                X + (size_t)(bn + r) * D_K + k0 + lk);
            Bs[lk + 0][r] = vb.x; Bs[lk + 1][r] = vb.y;
            Bs[lk + 2][r] = vb.z; Bs[lk + 3][r] = vb.w;
        }
        __syncthreads();
        #pragma unroll
        for (int k = 0; k < BK; ++k) {
            float4 alo = *reinterpret_cast<const float4*>(&As[k][ty << 3]);
            float4 ahi = *reinterpret_cast<const float4*>(&As[k][(ty << 3) + 4]);
            float4 blo = *reinterpret_cast<const float4*>(&Bs[k][tx << 3]);
            float4 bhi = *reinterpret_cast<const float4*>(&Bs[k][(tx << 3) + 4]);
            float a[8] = {alo.x, alo.y, alo.z, alo.w, ahi.x, ahi.y, ahi.z, ahi.w};
            float b[8] = {blo.x, blo.y, blo.z, blo.w, bhi.x, bhi.y, bhi.z, bhi.w};
            #pragma unroll
            for (int i = 0; i < 8; ++i)
                #pragma unroll
                for (int j = 0; j < 8; ++j)
                    acc[i][j] = fmaf(a[i], b[j], acc[i][j]);
        }
        __syncthreads();
    }

    // -------- epilogue: dist + masked row max/min ------------------------
    const int rows0 = bm + (ty << 3);
    const int cols0 = bn + (tx << 3);
    int   trow[8], tcol[8];
    float sqr[8],  sqc[8];
    #pragma unroll
    for (int i = 0; i < 8; ++i) { trow[i] = tgt[rows0 + i]; sqr[i] = sq[rows0 + i]; }
    #pragma unroll
    for (int j = 0; j < 8; ++j) { tcol[j] = tgt[cols0 + j]; sqc[j] = sq[cols0 + j]; }

    const float INF = __int_as_float(0x7f800000);
    float rap[8], ran[8];
    #pragma unroll
    for (int i = 0; i < 8; ++i) { rap[i] = -INF; ran[i] = INF; }
    #pragma unroll
    for (int i = 0; i < 8; ++i) {
        #pragma unroll
        for (int j = 0; j < 8; ++j) {
            float d = sqr[i] + sqc[j] - 2.f * acc[i][j];
            if (trow[i] == tcol[j]) rap[i] = fmaxf(rap[i], d);
            else                    ran[i] = fminf(ran[i], d);
        }
    }

    __syncthreads();
    float* redap = &As[0][0];  // reuse LDS: 128 rows x 16 tx
    float* redan = &Bs[0][0];
    #pragma unroll
    for (int i = 0; i < 8; ++i) {
        redap[((ty << 3) + i) * 16 + tx] = rap[i];
        redan[((ty << 3) + i) * 16 + tx] = ran[i];
    }
    __syncthreads();
    if (tid < 128) {
        float ap = -INF, an = INF;
        #pragma unroll
        for (int t = 0; t < 16; ++t) {
            ap = fmaxf(ap, redap[tid * 16 + t]);
            an = fminf(an, redan[tid * 16 + t]);
        }
        atomicMax(&apk[bm + tid], fkey(ap));
        atomicMin(&ank[bm + tid], fkey(an));
    }
}

// ---------------- kernel 3: loss + precision -------------------------------
__global__ __launch_bounds__(256) void final_kernel(const unsigned* __restrict__ apk,
        const unsigned* __restrict__ ank, float* __restrict__ out) {
    __shared__ float s_sum[4], s_cnt[4];
    float sum = 0.f, cnt = 0.f;
    for (int i = threadIdx.x; i < B_N; i += 256) {
        float ap = kval(apk[i]);
        float an = kval(ank[i]);
        float v  = ap - an + MARGIN;
        if (v > 0.f)  sum += v;
        if (an > ap)  cnt += 1.f;
    }
    #pragma unroll
    for (int off = 32; off > 0; off >>= 1) {
        sum += __shfl_down(sum, off, 64);
        cnt += __shfl_down(cnt, off, 64);
    }
    int wave = threadIdx.x >> 6, lane = threadIdx.x & 63;
    if (lane == 0) { s_sum[wave] = sum; s_cnt[wave] = cnt; }
    __syncthreads();
    if (threadIdx.x == 0) {
        float ts = 0.f, tc = 0.f;
        #pragma unroll
        for (int w = 0; w < 4; ++w) { ts += s_sum[w]; tc += s_cnt[w]; }
        out[0] = ts / (float)B_N;   // loss
        out[1] = tc / (float)B_N;   // prec
    }
}

extern "C" void kernel_launch(void* const* d_in, const int* in_sizes, int n_in,
                              void* d_out, int out_size, void* d_ws, size_t ws_size,
                              hipStream_t stream) {
    const float* X   = (const float*)d_in[0];
    const int*   tgt = (const int*)d_in[1];

    float*    sq  = (float*)d_ws;
    unsigned* apk = (unsigned*)((char*)d_ws + (size_t)B_N * 4);
    unsigned* ank = (unsigned*)((char*)d_ws + (size_t)B_N * 8);
    float*    out = (float*)d_out;

    prep_kernel<<<B_N / 4, 256, 0, stream>>>(X, sq, apk, ank);
    dist_kernel<<<dim3(B_N / BN, B_N / BM), 256, 0, stream>>>(X, tgt, sq, apk, ank);
    final_kernel<<<1, 256, 0, stream>>>(apk, ank, out);
}

// Round 2
// 213.326 us; speedup vs baseline: 2.1651x; 2.1651x over previous
//
#include <hip/hip_runtime.h>
#include <hip/hip_bf16.h>

#define B_N 8192
#define D_K 256
#define MARGIN 0.3f

typedef float  f32x4  __attribute__((ext_vector_type(4)));
typedef short  s16x8  __attribute__((ext_vector_type(8)));

// Order-preserving float->uint for atomicMax/atomicMin on floats.
__device__ __forceinline__ unsigned fkey(float f) {
    unsigned u = __float_as_uint(f);
    return (u & 0x80000000u) ? ~u : (u | 0x80000000u);
}
__device__ __forceinline__ float kval(unsigned k) {
    return (k & 0x80000000u) ? __uint_as_float(k ^ 0x80000000u)
                             : __uint_as_float(~k);
}

__device__ __forceinline__ unsigned short bfbits(float f) {
    __hip_bfloat16 h = __float2bfloat16(f);
    return *reinterpret_cast<unsigned short*>(&h);
}

// ---------------- kernel 1: norms + bf16 hi/lo split + init ---------------
__global__ __launch_bounds__(256) void prep_kernel(const float* __restrict__ X,
        float* __restrict__ sq, unsigned* __restrict__ apk,
        unsigned* __restrict__ ank, unsigned short* __restrict__ Xhi,
        unsigned short* __restrict__ Xlo) {
    int row  = (blockIdx.x << 2) + (threadIdx.x >> 6);  // 4 waves = 4 rows
    int lane = threadIdx.x & 63;
    const float4 v = reinterpret_cast<const float4*>(X + (size_t)row * D_K)[lane];
    float s = v.x * v.x + v.y * v.y + v.z * v.z + v.w * v.w;

    // split: x = hi + lo (both bf16), lo = bf16(x - float(hi))
    float xs[4] = {v.x, v.y, v.z, v.w};
    ushort4 hv, lv;
    unsigned short* hp = &hv.x; unsigned short* lp = &lv.x;
    #pragma unroll
    for (int i = 0; i < 4; ++i) {
        __hip_bfloat16 h = __float2bfloat16(xs[i]);
        hp[i] = *reinterpret_cast<unsigned short*>(&h);
        lp[i] = bfbits(xs[i] - __bfloat162float(h));
    }
    size_t off = (size_t)row * D_K + lane * 4;
    *reinterpret_cast<ushort4*>(Xhi + off) = hv;
    *reinterpret_cast<ushort4*>(Xlo + off) = lv;

    #pragma unroll
    for (int o = 32; o > 0; o >>= 1) s += __shfl_down(s, o, 64);
    if (lane == 0) {
        sq[row]  = s;
        apk[row] = 0u;           // <= fkey(-inf)
        ank[row] = 0xFFFFFFFFu;  // >= fkey(+inf)
    }
}

// ---------------- kernel 2: symmetric MFMA dist + fused mining -------------
#define BM 128
#define BN 128
#define BK 32
#define LDW 40   // 32 + 8 bf16 pad: 80B row stride, keeps 16B alignment

__global__ __launch_bounds__(256) void dist_kernel(
        const unsigned short* __restrict__ Xhi,
        const unsigned short* __restrict__ Xlo,
        const int* __restrict__ tgt, const float* __restrict__ sq,
        unsigned* __restrict__ apk, unsigned* __restrict__ ank) {
    if (blockIdx.y > blockIdx.x) return;   // upper-triangular blocks only
    const int bm = blockIdx.y * BM;        // bm <= bn
    const int bn = blockIdx.x * BN;

    __shared__ unsigned short Ahi[BM][LDW], Alo[BM][LDW];
    __shared__ unsigned short Bhi[BN][LDW], Blo[BN][LDW];
    __shared__ int   s_trow[BM], s_tcol[BN];
    __shared__ float s_sqr[BM],  s_sqc[BN];

    const int t    = threadIdx.x;
    const int lane = t & 63;
    const int wave = t >> 6;
    const int wrow = (wave >> 1) * 64;
    const int wcol = (wave & 1) * 64;
    const int fr   = lane & 15;   // MFMA row/col within 16-tile
    const int quad = lane >> 4;   // 0..3

    if (t < 128) { s_trow[t] = tgt[bm + t]; s_sqr[t] = sq[bm + t]; }
    else { s_tcol[t - 128] = tgt[bn + t - 128]; s_sqc[t - 128] = sq[bn + t - 128]; }

    f32x4 acc[4][4];
    #pragma unroll
    for (int i = 0; i < 4; ++i)
        #pragma unroll
        for (int j = 0; j < 4; ++j) acc[i][j] = (f32x4){0.f, 0.f, 0.f, 0.f};

    const int sr  = t >> 1;          // staging row 0..127
    const int k8b = (t & 1) * 2;     // staging k8 pair {0,1} or {2,3}
    const size_t arow = (size_t)(bm + sr) * D_K;
    const size_t brow = (size_t)(bn + sr) * D_K;

    #pragma unroll 1
    for (int k0 = 0; k0 < D_K; k0 += BK) {
        __syncthreads();  // previous-iter fragment reads done (also covers s_trow)
        #pragma unroll
        for (int p = 0; p < 2; ++p) {
            int k8 = k8b + p;
            int ge = k0 + k8 * 8;
            *reinterpret_cast<s16x8*>(&Ahi[sr][k8 * 8]) =
                *reinterpret_cast<const s16x8*>(Xhi + arow + ge);
            *reinterpret_cast<s16x8*>(&Alo[sr][k8 * 8]) =
                *reinterpret_cast<const s16x8*>(Xlo + arow + ge);
            *reinterpret_cast<s16x8*>(&Bhi[sr][k8 * 8]) =
                *reinterpret_cast<const s16x8*>(Xhi + brow + ge);
            *reinterpret_cast<s16x8*>(&Blo[sr][k8 * 8]) =
                *reinterpret_cast<const s16x8*>(Xlo + brow + ge);
        }
        __syncthreads();

        s16x8 a_hi[4], a_lo[4], b_hi[4], b_lo[4];
        #pragma unroll
        for (int mi = 0; mi < 4; ++mi) {
            int r = wrow + mi * 16 + fr;
            a_hi[mi] = *reinterpret_cast<const s16x8*>(&Ahi[r][quad * 8]);
            a_lo[mi] = *reinterpret_cast<const s16x8*>(&Alo[r][quad * 8]);
        }
        #pragma unroll
        for (int ni = 0; ni < 4; ++ni) {
            int c = wcol + ni * 16 + fr;
            b_hi[ni] = *reinterpret_cast<const s16x8*>(&Bhi[c][quad * 8]);
            b_lo[ni] = *reinterpret_cast<const s16x8*>(&Blo[c][quad * 8]);
        }
        #pragma unroll
        for (int mi = 0; mi < 4; ++mi)
            #pragma unroll
            for (int ni = 0; ni < 4; ++ni) {
                acc[mi][ni] = __builtin_amdgcn_mfma_f32_16x16x32_bf16(
                    a_hi[mi], b_hi[ni], acc[mi][ni], 0, 0, 0);
                acc[mi][ni] = __builtin_amdgcn_mfma_f32_16x16x32_bf16(
                    a_hi[mi], b_lo[ni], acc[mi][ni], 0, 0, 0);
                acc[mi][ni] = __builtin_amdgcn_mfma_f32_16x16x32_bf16(
                    a_lo[mi], b_hi[ni], acc[mi][ni], 0, 0, 0);
            }
    }

    // -------- epilogue: dist + row mining (this block's rows) + col mining
    // (this block's cols = rows of the transposed half) ---------------------
    const float INF = __int_as_float(0x7f800000);
    int   ct[4]; float csq[4];
    #pragma unroll
    for (int ni = 0; ni < 4; ++ni) {
        int cl = wcol + ni * 16 + fr;
        ct[ni] = s_tcol[cl]; csq[ni] = s_sqc[cl];
    }
    float cap[4], can[4];
    #pragma unroll
    for (int ni = 0; ni < 4; ++ni) { cap[ni] = -INF; can[ni] = INF; }

    #pragma unroll
    for (int mi = 0; mi < 4; ++mi) {
        #pragma unroll
        for (int reg = 0; reg < 4; ++reg) {
            int rl = wrow + mi * 16 + quad * 4 + reg;
            int rt = s_trow[rl]; float rsq = s_sqr[rl];
            float rap = -INF, ran = INF;
            #pragma unroll
            for (int ni = 0; ni < 4; ++ni) {
                float d = rsq + csq[ni] - 2.f * acc[mi][ni][reg];
                bool pos = (rt == ct[ni]);
                if (pos) { rap = fmaxf(rap, d); cap[ni] = fmaxf(cap[ni], d); }
                else     { ran = fminf(ran, d); can[ni] = fminf(can[ni], d); }
            }
            #pragma unroll
            for (int o = 1; o < 16; o <<= 1) {
                rap = fmaxf(rap, __shfl_xor(rap, o, 64));
                ran = fminf(ran, __shfl_xor(ran, o, 64));
            }
            if (fr == 0) {
                atomicMax(&apk[bm + rl], fkey(rap));
                atomicMin(&ank[bm + rl], fkey(ran));
            }
        }
    }
    #pragma unroll
    for (int ni = 0; ni < 4; ++ni) {
        #pragma unroll
        for (int o = 16; o < 64; o <<= 1) {
            cap[ni] = fmaxf(cap[ni], __shfl_xor(cap[ni], o, 64));
            can[ni] = fminf(can[ni], __shfl_xor(can[ni], o, 64));
        }
    }
    if (lane < 16) {
        #pragma unroll
        for (int ni = 0; ni < 4; ++ni) {
            int c = bn + wcol + ni * 16 + lane;
            atomicMax(&apk[c], fkey(cap[ni]));
            atomicMin(&ank[c], fkey(can[ni]));
        }
    }
}

// ---------------- kernel 3: loss + precision -------------------------------
__global__ __launch_bounds__(256) void final_kernel(const unsigned* __restrict__ apk,
        const unsigned* __restrict__ ank, float* __restrict__ out) {
    __shared__ float s_sum[4], s_cnt[4];
    float sum = 0.f, cnt = 0.f;
    for (int i = threadIdx.x; i < B_N; i += 256) {
        float ap = kval(apk[i]);
        float an = kval(ank[i]);
        float v  = ap - an + MARGIN;
        if (v > 0.f)  sum += v;
        if (an > ap)  cnt += 1.f;
    }
    #pragma unroll
    for (int o = 32; o > 0; o >>= 1) {
        sum += __shfl_down(sum, o, 64);
        cnt += __shfl_down(cnt, o, 64);
    }
    int wave = threadIdx.x >> 6, lane = threadIdx.x & 63;
    if (lane == 0) { s_sum[wave] = sum; s_cnt[wave] = cnt; }
    __syncthreads();
    if (threadIdx.x == 0) {
        float ts = 0.f, tc = 0.f;
        #pragma unroll
        for (int w = 0; w < 4; ++w) { ts += s_sum[w]; tc += s_cnt[w]; }
        out[0] = ts / (float)B_N;
        out[1] = tc / (float)B_N;
    }
}

extern "C" void kernel_launch(void* const* d_in, const int* in_sizes, int n_in,
                              void* d_out, int out_size, void* d_ws, size_t ws_size,
                              hipStream_t stream) {
    const float* X   = (const float*)d_in[0];
    const int*   tgt = (const int*)d_in[1];

    char* ws = (char*)d_ws;
    float*          sq  = (float*)ws;                        // 32 KB
    unsigned*       apk = (unsigned*)(ws + 32768);           // 32 KB
    unsigned*       ank = (unsigned*)(ws + 65536);           // 32 KB
    unsigned short* Xhi = (unsigned short*)(ws + 98304);     // 4 MB
    unsigned short* Xlo = (unsigned short*)(ws + 98304 + (size_t)B_N * D_K * 2);
    float* out = (float*)d_out;

    prep_kernel<<<B_N / 4, 256, 0, stream>>>(X, sq, apk, ank, Xhi, Xlo);
    dist_kernel<<<dim3(B_N / BN, B_N / BM), 256, 0, stream>>>(Xhi, Xlo, tgt, sq, apk, ank);
    final_kernel<<<1, 256, 0, stream>>>(apk, ank, out);
}